// Round 2
// baseline (416.591 us; speedup 1.0000x reference)
//
#include <hip/hip_runtime.h>
#include <hip/hip_bf16.h>

// CrossAttention with KV length 1: softmax over a size-1 axis == 1.0, so
// Q/K projections are dead. out[b,n,:] = (freq[b] @ Wv.T + bv) @ Wo.T + bo,
// broadcast over all n. Single fused kernel: each block recomputes the
// per-batch O2 row (weights are L2-resident per XCD, so redundancy is cheap)
// and streams its output chunk. One dispatch => no inter-kernel gaps.

#define B_    16
#define N_    4096
#define CSP   768
#define CFD   512
#define ROWS_PER_BLK 256          // N_/16 -> grid (16,16) = 256 blocks, 1/CU
#define TPB   768                 // 12 waves

__global__ void __launch_bounds__(TPB) fused_cross_attn(
    const float* __restrict__ freq,   // [B, CFD]
    const float* __restrict__ Wv,     // [CSP, CFD]
    const float* __restrict__ bv,     // [CSP]
    const float* __restrict__ Wo,     // [CSP, CSP]
    const float* __restrict__ bo,     // [CSP]
    float* __restrict__ out)          // [B, N, CSP]
{
    const int b     = blockIdx.x;
    const int chunk = blockIdx.y;
    const int t     = threadIdx.x;

    __shared__ __align__(16) float sF[CFD];   // freq row
    __shared__ __align__(16) float sV[CSP];   // V = freq @ Wv.T + bv
    __shared__ __align__(16) float sO[CSP];   // O2 = V @ Wo.T + bo

    if (t < CFD) sF[t] = freq[(size_t)b * CFD + t];
    __syncthreads();

    // Phase 1: V[t] = bv[t] + dot(freq[b], Wv[t,:])   (one output per thread)
    {
        float acc = bv[t];
        const float4* wr = (const float4*)Wv + (size_t)t * (CFD / 4);
        const float4* fr = (const float4*)sF;
#pragma unroll 8
        for (int i = 0; i < CFD / 4; ++i) {
            float4 w = wr[i];
            float4 f = fr[i];
            acc += w.x * f.x + w.y * f.y + w.z * f.z + w.w * f.w;
        }
        sV[t] = acc;
    }
    __syncthreads();

    // Phase 2: O2[t] = bo[t] + dot(V, Wo[t,:])
    {
        float acc = bo[t];
        const float4* wr = (const float4*)Wo + (size_t)t * (CSP / 4);
        const float4* vr = (const float4*)sV;
#pragma unroll 8
        for (int i = 0; i < CSP / 4; ++i) {
            float4 w = wr[i];
            float4 v = vr[i];
            acc += w.x * v.x + w.y * v.y + w.z * v.z + w.w * v.w;
        }
        sO[t] = acc;
    }
    __syncthreads();

    // Phase 3: broadcast O2 row over ROWS_PER_BLK output rows.
    // 768 threads = 192 float4-cols x 4 row-phases; fully coalesced stores.
    const int col4 = t % (CSP / 4);   // 0..191
    const int r0   = t / (CSP / 4);   // 0..3
    const float4 v = ((const float4*)sO)[col4];

    float4* dst = (float4*)(out + ((size_t)b * N_ + (size_t)chunk * ROWS_PER_BLK) * CSP) + col4;
#pragma unroll 8
    for (int r = r0; r < ROWS_PER_BLK; r += 4)
        dst[(size_t)r * (CSP / 4)] = v;
}

extern "C" void kernel_launch(void* const* d_in, const int* in_sizes, int n_in,
                              void* d_out, int out_size, void* d_ws, size_t ws_size,
                              hipStream_t stream) {
    // Inputs (setup_inputs order):
    // 0: spatial_tokens (dead)  1: freq_token [B,CFD]
    // 2: Wq (dead) 3: bq (dead) 4: Wk (dead) 5: bk (dead)
    // 6: Wv [CSP,CFD] 7: bv [CSP] 8: Wo [CSP,CSP] 9: bo [CSP]
    const float* freq = (const float*)d_in[1];
    const float* Wv   = (const float*)d_in[6];
    const float* bv   = (const float*)d_in[7];
    const float* Wo   = (const float*)d_in[8];
    const float* bo   = (const float*)d_in[9];
    float* out = (float*)d_out;

    fused_cross_attn<<<dim3(B_, N_ / ROWS_PER_BLK), TPB, 0, stream>>>(
        freq, Wv, bv, Wo, bo, out);
}